// Round 12
// baseline (641.368 us; speedup 1.0000x reference)
//
#include <hip/hip_runtime.h>
#include <math.h>

namespace {

constexpr int NN  = 50000;
constexpr int CC  = 128;
constexpr int EMn = 1000000;
constexpr int ESn = 200000;
constexpr int MLPB = 256;            // persistent blocks
constexpr int WPB  = 12;             // waves per block
constexpr int NTILES = ESn / 16;     // 12500 tiles of 16 edges
constexpr int NWAVES = MLPB * WPB;   // 3072

using i32x4 = __attribute__((ext_vector_type(4))) int;

__device__ __forceinline__ float softplusf(float x) {
  return (x > 20.f) ? x : log1pf(expf(x));
}
__device__ __forceinline__ int sdot4i(unsigned a, unsigned b, int c) {
#if __has_builtin(__builtin_amdgcn_sdot4)
  return __builtin_amdgcn_sdot4((int)a, (int)b, c, false);
#else
  int r = c;
#pragma unroll
  for (int k = 0; k < 4; k++) {
    int xa = ((int)(a << (24 - 8 * k))) >> 24;
    int xb = ((int)(b << (24 - 8 * k))) >> 24;
    r += xa * xb;
  }
  return r;
#endif
}
__device__ __forceinline__ unsigned pack4(float a, float b, float c, float d) {
  int ia = __float2int_rn(a), ib = __float2int_rn(b);
  int ic = __float2int_rn(c), id = __float2int_rn(d);
  return (unsigned)(ia & 255) | ((unsigned)(ib & 255) << 8) |
         ((unsigned)(ic & 255) << 16) | ((unsigned)(id & 255) << 24);
}

// ---- K0: init scratch (incl. zeroing qunit dump row NN) ----
__global__ void k_init(int* __restrict__ pidx, double* __restrict__ dencnt,
                       float* __restrict__ num, char* __restrict__ qunit) {
  int i = blockIdx.x * blockDim.x + threadIdx.x;
  if (i < NN) pidx[i] = -1;
  if (i <= NN) { dencnt[i] = 0.0; num[i] = 0.f; }
  if (i < CC / 4) ((unsigned*)(qunit + (size_t)NN * CC))[i] = 0u;
}

// ---- K_cvtq: per-row int8 quantization of nodes/nbrs ----
__global__ void k_cvtq(const float* __restrict__ nodes, const float* __restrict__ nbrs,
                       char* __restrict__ qnodes, char* __restrict__ qunit,
                       char* __restrict__ qnbrs, float* __restrict__ nscale,
                       float* __restrict__ nbscale) {
  int row = blockIdx.x * 16 + (threadIdx.x >> 4);
  int li = threadIdx.x & 15;
  if (row >= 2 * NN) return;
  bool isn = row < NN;
  int r = isn ? row : row - NN;
  const float* src = (isn ? nodes : nbrs) + (size_t)r * CC;
  float4 x0 = *(const float4*)(src + li * 8);
  float4 x1 = *(const float4*)(src + li * 8 + 4);
  float v[8] = {x0.x, x0.y, x0.z, x0.w, x1.x, x1.y, x1.z, x1.w};
  float amax = 0.f, sq = 0.f;
#pragma unroll
  for (int j = 0; j < 8; j++) { amax = fmaxf(amax, fabsf(v[j])); sq += v[j] * v[j]; }
#pragma unroll
  for (int off = 1; off < 16; off <<= 1) {
    amax = fmaxf(amax, __shfl_xor(amax, off, 64));
    sq += __shfl_xor(sq, off, 64);
  }
  amax = fmaxf(amax, 1e-8f);
  float rs = 127.f / amax;
  uint2 p;
  p.x = pack4(v[0] * rs, v[1] * rs, v[2] * rs, v[3] * rs);
  p.y = pack4(v[4] * rs, v[5] * rs, v[6] * rs, v[7] * rs);
  if (isn) {
    *(uint2*)(qnodes + (size_t)r * CC + li * 8) = p;
    float ru = 127.f / fmaxf(sqrtf(sq), 1e-8f);
    uint2 pu;
    pu.x = pack4(v[0] * ru, v[1] * ru, v[2] * ru, v[3] * ru);
    pu.y = pack4(v[4] * ru, v[5] * ru, v[6] * ru, v[7] * ru);
    *(uint2*)(qunit + (size_t)r * CC + li * 8) = pu;
    if (li == 0) nscale[r] = amax / 127.f;
  } else {
    *(uint2*)(qnbrs + (size_t)r * CC + li * 8) = p;
    if (li == 0) nbscale[r] = amax / 127.f;
  }
}

// ---- K2: partner_index scatter-max ----
__global__ void k_partner(const int* __restrict__ ss, const int* __restrict__ sd,
                          int* __restrict__ pidx) {
  int i = blockIdx.x * blockDim.x + threadIdx.x;
  if (i >= 2 * ESn) return;
  int partner = (i < ESn) ? sd[i] : ss[i - ESn];
  atomicMax(&pidx[partner], i);
}

// ---- K_qnode ----
__global__ void k_qnode(const int* __restrict__ pidx, const int* __restrict__ ss,
                        const int* __restrict__ sd, int* __restrict__ qnode) {
  int n = blockIdx.x * blockDim.x + threadIdx.x;
  if (n >= NN) return;
  int pi = pidx[n];
  qnode[n] = (pi < 0) ? -1 : ((pi < ESn) ? ss[pi] : sd[pi - ESn]);
}

// ---- K_qedge: per-msg-edge query (NN = dump slot) ----
__global__ void k_qedge(const int* __restrict__ md, const int* __restrict__ qnode,
                        int* __restrict__ qedge) {
  int e = blockIdx.x * blockDim.x + threadIdx.x;
  if (e >= EMn) return;
  int q = qnode[md[e]];
  qedge[e] = (q < 0) ? NN : q;
}

// ---- K_prep2: int8 per-col quant of W0/W1 into LINEAR [col][k] layout ----
__global__ __launch_bounds__(256) void k_prep2(const float* __restrict__ W0,
                                               const float* __restrict__ W1,
                                               char* __restrict__ w0q, char* __restrict__ w1q,
                                               float* __restrict__ cs0, float* __restrict__ cs1) {
  __shared__ float wmax[4];
  int c = blockIdx.x;
  int k = threadIdx.x;
  bool is0 = c < 256;
  int col = is0 ? c : c - 256;
  float v = is0 ? W0[(size_t)k * 256 + col] : W1[(size_t)k * 128 + col];
  float am = fabsf(v);
#pragma unroll
  for (int off = 1; off < 64; off <<= 1) am = fmaxf(am, __shfl_xor(am, off, 64));
  if ((k & 63) == 0) wmax[k >> 6] = am;
  __syncthreads();
  float amax = fmaxf(fmaxf(wmax[0], wmax[1]), fmaxf(wmax[2], wmax[3]));
  amax = fmaxf(amax, 1e-12f);
  int q = __float2int_rn(v * (127.f / amax));
  char* dst = is0 ? w0q : w1q;
  dst[(size_t)col * 256 + k] = (char)q;
  if (k == 0) (is0 ? cs0 : cs1)[col] = amax / 127.f;
}

// ---- K5: cong_node (decode packed den+cnt) ----
__global__ void k_cong(const double* __restrict__ dencnt, const float* __restrict__ num,
                       float* __restrict__ cong) {
  int n = blockIdx.x * blockDim.x + threadIdx.x;
  if (n >= NN) return;
  double dc = dencnt[n];
  double cnt = floor(dc * (1.0 / 4294967296.0) + 0.5);
  double den = dc - cnt * 4294967296.0;
  cong[n] = (cnt > 0.0) ? (float)(((double)num[n] / fmax(den, 1e-30)) / cnt) : 0.f;
}

// ---- K_finish: P_cong column + coeff ----
__global__ void k_finish(const int* __restrict__ ssrc, const int* __restrict__ sdst,
                         const float* __restrict__ cong, const float* __restrict__ sscale,
                         const float* __restrict__ sshift, const float* __restrict__ craw,
                         float* __restrict__ out) {
  int i = blockIdx.x * blockDim.x + threadIdx.x;
  float u0 = softplusf(craw[0]), u1 = softplusf(craw[1]), u2 = softplusf(craw[2]);
  float usum = u0 + u1 + u2;
  float c2 = u2 / usum;
  if (i < ESn)
    out[3 * i + 2] = c2 * (sscale[0] * (cong[ssrc[i]] + cong[sdst[i]] + sshift[0]));
  if (i == 0) {
    out[4 * ESn + 0] = u0 / usum;
    out[4 * ESn + 1] = u1 / usum;
    out[4 * ESn + 2] = c2;
  }
}

// ---- K_big: wave-autonomous MLP (weights streamed from L2) + cos phase ----
// LDS = prm(7K) + hln(48K) = 56K -> 2 blocks/CU, 24 waves/CU.
__global__ __launch_bounds__(768, 2) void k_big(
    const char* __restrict__ qnodes, const float* __restrict__ nscale,
    const char* __restrict__ qnbrs, const float* __restrict__ nbscale,
    const char* __restrict__ qunit, const int* __restrict__ qedge,
    const int* __restrict__ ssrc, const int* __restrict__ sdst,
    const int* __restrict__ ms,
    double* __restrict__ dencnt, float* __restrict__ num,
    const char* __restrict__ w0q, const char* __restrict__ w1q,
    const float* __restrict__ cs0g, const float* __restrict__ cs1g,
    const float* __restrict__ b0, const float* __restrict__ g0, const float* __restrict__ be0,
    const float* __restrict__ b1, const float* __restrict__ g1, const float* __restrict__ be1,
    const float* __restrict__ Wp, const float* __restrict__ bp,
    const float* __restrict__ Ww, const float* __restrict__ bw,
    const float* __restrict__ sscale, const float* __restrict__ sshift,
    const float* __restrict__ craw, float* __restrict__ out) {
  __shared__ float prm[1792];
  __shared__ char  hln[WPB][4096];   // per-wave h_ln int8 [16 r][256 c] swizzled

  const int t = threadIdx.x;
  if (t < 256) { prm[t] = cs0g[t]; prm[256 + t] = b0[t]; prm[512 + t] = g0[t]; prm[768 + t] = be0[t]; }
  if (t < 128) { prm[1024 + t] = cs1g[t]; prm[1152 + t] = b1[t]; prm[1280 + t] = g1[t];
                 prm[1408 + t] = be1[t];  prm[1536 + t] = Wp[t]; prm[1664 + t] = Ww[t]; }
  __syncthreads();                   // the ONLY block barrier

  const int wv = t >> 6, l = t & 63;
  const int e16 = l & 15, ch = l >> 4;
  const int gw = blockIdx.x * WPB + wv;
  char* hw = hln[wv];

  float u0 = softplusf(craw[0]), u1 = softplusf(craw[1]), u2 = softplusf(craw[2]);
  float us = u0 + u1 + u2, c0 = u0 / us, c1 = u1 / us;
  float sc = sscale[0], sh = sshift[0], bp0 = bp[0], bw0 = bw[0], ww128 = Ww[128];

  // ---- MLP phase with cross-tile gather prefetch (no barriers in loop) ----
  int tile = gw;
  float sxs = 0.f, sxd = 0.f, nbs = 0.f;
  uint4 X0 = {}, X1 = {}, Y0 = {}, Y1 = {}, NX0 = {}, NX1 = {}, NY0 = {}, NY1 = {};
  if (tile < NTILES) {
    int eg = tile * 16 + e16;
    int es = ssrc[eg], ed = sdst[eg];
    sxs = nscale[es]; sxd = nscale[ed];
    nbs = nbscale[es] * nbscale[ed];
    const uint4* xp = (const uint4*)(qnodes + (size_t)es * CC);
    const uint4* yp = (const uint4*)(qnodes + (size_t)ed * CC);
    X0 = xp[ch]; X1 = xp[4 + ch]; Y0 = yp[ch]; Y1 = yp[4 + ch];
    const uint4* nxp = (const uint4*)(qnbrs + (size_t)es * CC);
    const uint4* nyp = (const uint4*)(qnbrs + (size_t)ed * CC);
    NX0 = nxp[2 * ch]; NX1 = nxp[2 * ch + 1]; NY0 = nyp[2 * ch]; NY1 = nyp[2 * ch + 1];
  }

  while (tile < NTILES) {
    const int s0 = tile * 16;

    // ---- nsim from prefetched data ----
    int sa = 0;
    sa = sdot4i(NX0.x, NY0.x, sa); sa = sdot4i(NX0.y, NY0.y, sa);
    sa = sdot4i(NX0.z, NY0.z, sa); sa = sdot4i(NX0.w, NY0.w, sa);
    sa = sdot4i(NX1.x, NY1.x, sa); sa = sdot4i(NX1.y, NY1.y, sa);
    sa = sdot4i(NX1.z, NY1.z, sa); sa = sdot4i(NX1.w, NY1.w, sa);
    sa += __shfl_xor(sa, 16, 64); sa += __shfl_xor(sa, 32, 64);
    float nsim = (float)sa * nbs;

    unsigned xw[8] = {X0.x, X0.y, X0.z, X0.w, X1.x, X1.y, X1.z, X1.w};
    unsigned yw[8] = {Y0.x, Y0.y, Y0.z, Y0.w, Y1.x, Y1.y, Y1.z, Y1.w};

    // ---- row amax of combined (a|m) ----
    float amax = 1e-8f;
#pragma unroll
    for (int d = 0; d < 8; d++)
#pragma unroll
      for (int b = 0; b < 4; b++) {
        float fx = (float)((int)(xw[d] << (24 - 8 * b)) >> 24) * sxs;
        float fy = (float)((int)(yw[d] << (24 - 8 * b)) >> 24) * sxd;
        amax = fmaxf(amax, fmaxf(fabsf(fx + fy), fabsf(fx * fy)));
      }
    amax = fmaxf(amax, __shfl_xor(amax, 16, 64));
    amax = fmaxf(amax, __shfl_xor(amax, 32, 64));
    float rqz = 127.f / amax, rsc = amax / 127.f;

    // ---- build 4 int8 A-frags ----
    i32x4 fr[4];
#pragma unroll
    for (int half = 0; half < 2; half++) {
#pragma unroll
      for (int d = 0; d < 4; d++) {
        unsigned xd = xw[half * 4 + d], yd = yw[half * 4 + d];
        float a_[4], m_[4];
#pragma unroll
        for (int b = 0; b < 4; b++) {
          float fx = (float)((int)(xd << (24 - 8 * b)) >> 24) * sxs;
          float fy = (float)((int)(yd << (24 - 8 * b)) >> 24) * sxd;
          a_[b] = fx + fy; m_[b] = fx * fy;
        }
        fr[half][d]     = (int)pack4(a_[0] * rqz, a_[1] * rqz, a_[2] * rqz, a_[3] * rqz);
        fr[2 + half][d] = (int)pack4(m_[0] * rqz, m_[1] * rqz, m_[2] * rqz, m_[3] * rqz);
      }
    }
    float rsrow[4];
#pragma unroll
    for (int j = 0; j < 4; j++) rsrow[j] = __shfl(rsc, (ch << 2) + j, 64);

    // ---- PREFETCH next tile's gathers ----
    const int ntile = tile + NWAVES;
    if (ntile < NTILES) {
      int eg = ntile * 16 + e16;
      int es = ssrc[eg], ed = sdst[eg];
      sxs = nscale[es]; sxd = nscale[ed];
      nbs = nbscale[es] * nbscale[ed];
      const uint4* xp = (const uint4*)(qnodes + (size_t)es * CC);
      const uint4* yp = (const uint4*)(qnodes + (size_t)ed * CC);
      X0 = xp[ch]; X1 = xp[4 + ch]; Y0 = yp[ch]; Y1 = yp[4 + ch];
      const uint4* nxp = (const uint4*)(qnbrs + (size_t)es * CC);
      const uint4* nyp = (const uint4*)(qnbrs + (size_t)ed * CC);
      NX0 = nxp[2 * ch]; NX1 = nxp[2 * ch + 1]; NY0 = nyp[2 * ch]; NY1 = nyp[2 * ch + 1];
    }

    // ---- GEMM1: i8 MFMA, B-frags streamed from global (L2-resident) ----
    i32x4 acc[16];
#pragma unroll
    for (int nf = 0; nf < 16; nf++) acc[nf] = (i32x4){0, 0, 0, 0};
#pragma unroll
    for (int s = 0; s < 4; s++) {
      int kofs = (s * 4 + ch) << 4;
#pragma unroll
      for (int nf = 0; nf < 16; nf++) {
        i32x4 bfr = *(const i32x4*)&w0q[(size_t)(nf * 16 + e16) * 256 + kofs];
        acc[nf] = __builtin_amdgcn_mfma_i32_16x16x64_i8(fr[s], bfr, acc[nf], 0, 0, 0);
      }
    }

    // ---- LN1 stats ----
    float sj[4] = {0, 0, 0, 0}, qj[4] = {0, 0, 0, 0};
#pragma unroll
    for (int nf = 0; nf < 16; nf++) {
      float cs = prm[nf * 16 + e16], bb = prm[256 + nf * 16 + e16];
#pragma unroll
      for (int j = 0; j < 4; j++) {
        float h = (float)acc[nf][j] * rsrow[j] * cs + bb;
        sj[j] += h; qj[j] += h * h;
      }
    }
    float mu[4], rstd[4];
#pragma unroll
    for (int j = 0; j < 4; j++) {
      float s = sj[j], q = qj[j];
#pragma unroll
      for (int off = 1; off < 16; off <<= 1) { s += __shfl_xor(s, off, 64); q += __shfl_xor(q, off, 64); }
      mu[j] = s * (1.f / 256.f);
      rstd[j] = rsqrtf(q * (1.f / 256.f) - mu[j] * mu[j] + 1e-5f);
    }
    float hmax[4] = {1e-8f, 1e-8f, 1e-8f, 1e-8f};
#pragma unroll
    for (int nf = 0; nf < 16; nf++) {
      float cs = prm[nf * 16 + e16], bb = prm[256 + nf * 16 + e16];
      float gg = prm[512 + nf * 16 + e16], be = prm[768 + nf * 16 + e16];
#pragma unroll
      for (int j = 0; j < 4; j++) {
        float h = (float)acc[nf][j] * rsrow[j] * cs + bb;
        float v = fmaxf((h - mu[j]) * rstd[j] * gg + be, 0.f);
        hmax[j] = fmaxf(hmax[j], v);
        acc[nf][j] = __float_as_int(v);
      }
    }
    float rq2[4], rs2[4];
#pragma unroll
    for (int j = 0; j < 4; j++) {
      float m = hmax[j];
#pragma unroll
      for (int off = 1; off < 16; off <<= 1) m = fmaxf(m, __shfl_xor(m, off, 64));
      rq2[j] = 127.f / m; rs2[j] = m / 127.f;
    }
#pragma unroll
    for (int nf = 0; nf < 16; nf++) {
#pragma unroll
      for (int j = 0; j < 4; j++) {
        int r = (ch << 2) + j;
        int qv = __float2int_rn(__int_as_float(acc[nf][j]) * rq2[j]);
        hw[r * 256 + ((nf ^ r) << 4) + e16] = (char)qv;
      }
    }

    // ---- GEMM2: A from private LDS (swizzled), B streamed from global ----
    i32x4 acc2[8];
#pragma unroll
    for (int nf = 0; nf < 8; nf++) acc2[nf] = (i32x4){0, 0, 0, 0};
#pragma unroll
    for (int s = 0; s < 4; s++) {
      int gofs = (((s * 4 + ch) ^ e16) << 4);
      int kofs = (s * 4 + ch) << 4;
      i32x4 af = *(const i32x4*)&hw[e16 * 256 + gofs];
#pragma unroll
      for (int nf = 0; nf < 8; nf++) {
        i32x4 bfr = *(const i32x4*)&w1q[(size_t)(nf * 16 + e16) * 256 + kofs];
        acc2[nf] = __builtin_amdgcn_mfma_i32_16x16x64_i8(af, bfr, acc2[nf], 0, 0, 0);
      }
    }

    // ---- LN2 + heads ----
    float s2[4] = {0, 0, 0, 0}, q2[4] = {0, 0, 0, 0};
#pragma unroll
    for (int nf = 0; nf < 8; nf++) {
      float cs = prm[1024 + nf * 16 + e16], bb = prm[1152 + nf * 16 + e16];
#pragma unroll
      for (int j = 0; j < 4; j++) {
        float ef = (float)acc2[nf][j] * rs2[j] * cs + bb;
        s2[j] += ef; q2[j] += ef * ef;
      }
    }
    float mu2[4], rstd2[4];
#pragma unroll
    for (int j = 0; j < 4; j++) {
      float s = s2[j], q = q2[j];
#pragma unroll
      for (int off = 1; off < 16; off <<= 1) { s += __shfl_xor(s, off, 64); q += __shfl_xor(q, off, 64); }
      mu2[j] = s * (1.f / 128.f);
      rstd2[j] = rsqrtf(q * (1.f / 128.f) - mu2[j] * mu2[j] + 1e-5f);
    }
    float pd[4] = {0, 0, 0, 0}, ws_[4] = {0, 0, 0, 0};
#pragma unroll
    for (int nf = 0; nf < 8; nf++) {
      float cs = prm[1024 + nf * 16 + e16], bb = prm[1152 + nf * 16 + e16];
      float gg = prm[1280 + nf * 16 + e16], be = prm[1408 + nf * 16 + e16];
      float wp_ = prm[1536 + nf * 16 + e16], ww_ = prm[1664 + nf * 16 + e16];
#pragma unroll
      for (int j = 0; j < 4; j++) {
        float ef = (float)acc2[nf][j] * rs2[j] * cs + bb;
        float v = fmaxf((ef - mu2[j]) * rstd2[j] * gg + be, 0.f);
        pd[j] += v * wp_; ws_[j] += v * ww_;
      }
    }
#pragma unroll
    for (int j = 0; j < 4; j++)
#pragma unroll
      for (int off = 1; off < 16; off <<= 1) {
        pd[j] += __shfl_xor(pd[j], off, 64);
        ws_[j] += __shfl_xor(ws_[j], off, 64);
      }
    float nsr[4];
#pragma unroll
    for (int j = 0; j < 4; j++) nsr[j] = __shfl(nsim, (ch << 2) + j, 64);
    if (e16 == 0) {
#pragma unroll
      for (int j = 0; j < 4; j++) {
        int sidx = s0 + (ch << 2) + j;
        out[3 * sidx + 0] = c0 * (pd[j] + bp0);
        out[3 * sidx + 1] = c1 * (sc * (nsr[j] + sh));
        out[3 * ESn + sidx] = fmaxf(ws_[j] + nsr[j] * ww128 + bw0, 0.f);
      }
    }
    tile = ntile;
  }

  // ---- cos phase: branch-free, 4 lanes/edge ----
  const int li4 = l & 3, grp4 = l >> 2;
#pragma unroll 2
  for (int i = gw; i < EMn / 16; i += NWAVES) {
    int e = i * 16 + grp4;
    int q = qedge[e];                  // coalesced; NN = dump slot (zero row)
    int s = ms[e];
    const uint4* ap = (const uint4*)(qunit + (size_t)q * CC);
    const uint4* bp2 = (const uint4*)(qunit + (size_t)s * CC);
    uint4 a0 = ap[li4], a1 = ap[4 + li4];
    uint4 b0_ = bp2[li4], b1_ = bp2[4 + li4];
    int acc = 0;
    acc = sdot4i(a0.x, b0_.x, acc); acc = sdot4i(a0.y, b0_.y, acc);
    acc = sdot4i(a0.z, b0_.z, acc); acc = sdot4i(a0.w, b0_.w, acc);
    acc = sdot4i(a1.x, b1_.x, acc); acc = sdot4i(a1.y, b1_.y, acc);
    acc = sdot4i(a1.z, b1_.z, acc); acc = sdot4i(a1.w, b1_.w, acc);
    acc += __shfl_xor(acc, 1, 64);
    acc += __shfl_xor(acc, 2, 64);
    if (li4 == 0) {
      float cv = (float)acc * (1.0f / (127.f * 127.f));
      float wvv = exp2f(cv * 14.4269504089f);      // exp(10*cv)
      atomicAdd(&dencnt[q], (double)wvv + 4294967296.0);   // den + cnt*2^32 packed
      atomicAdd(&num[q], wvv * cv);
    }
  }
}

} // namespace

extern "C" void kernel_launch(void* const* d_in, const int* in_sizes, int n_in,
                              void* d_out, int out_size, void* d_ws, size_t ws_size,
                              hipStream_t stream) {
  (void)in_sizes; (void)n_in; (void)out_size; (void)ws_size;
  const float* nodes  = (const float*)d_in[0];
  const float* nbrs   = (const float*)d_in[1];
  const int* sup_src  = (const int*)d_in[2];
  const int* sup_dst  = (const int*)d_in[3];
  const int* msg_src  = (const int*)d_in[4];
  const int* msg_dst  = (const int*)d_in[5];
  // d_in[6] message_edgestr: dead
  const float* W0  = (const float*)d_in[7];
  const float* b0  = (const float*)d_in[8];
  const float* g0  = (const float*)d_in[9];
  const float* be0 = (const float*)d_in[10];
  const float* W1  = (const float*)d_in[11];
  const float* b1  = (const float*)d_in[12];
  const float* g1  = (const float*)d_in[13];
  const float* be1 = (const float*)d_in[14];
  const float* Wp  = (const float*)d_in[15];
  const float* bp  = (const float*)d_in[16];
  const float* Ww  = (const float*)d_in[17];
  const float* bw  = (const float*)d_in[18];
  const float* sscale = (const float*)d_in[19];
  const float* sshift = (const float*)d_in[20];
  const float* craw   = (const float*)d_in[21];
  // d_in[22..27] mm_*: dead
  float* out = (float*)d_out;

  char* p = (char*)d_ws;
  auto take = [&](size_t bytes) -> char* {
    char* r = p; p += (bytes + 255) & ~(size_t)255; return r;
  };
  char*   w0q     = take((size_t)256 * 256);
  char*   w1q     = take((size_t)128 * 256);
  float*  cs0     = (float*)take((size_t)256 * 4);
  float*  cs1     = (float*)take((size_t)128 * 4);
  char*   qnodes  = take((size_t)NN * CC);
  char*   qunit   = take((size_t)(NN + 1) * CC);
  char*   qnbrs   = take((size_t)NN * CC);
  float*  nscale  = (float*)take((size_t)NN * 4);
  float*  nbscale = (float*)take((size_t)NN * 4);
  int*    pidx    = (int*)take((size_t)NN * 4);
  int*    qnode   = (int*)take((size_t)NN * 4);
  int*    qedge   = (int*)take((size_t)EMn * 4);
  double* dencnt  = (double*)take((size_t)(NN + 1) * 8);
  float*  num     = (float*)take((size_t)(NN + 1) * 4);
  float*  cong    = (float*)take((size_t)NN * 4);

  k_init<<<(NN + 1 + 255) / 256, 256, 0, stream>>>(pidx, dencnt, num, qunit);
  k_cvtq<<<(2 * NN + 15) / 16, 256, 0, stream>>>(nodes, nbrs, qnodes, qunit, qnbrs,
                                                 nscale, nbscale);
  k_prep2<<<384, 256, 0, stream>>>(W0, W1, w0q, w1q, cs0, cs1);
  k_partner<<<(2 * ESn + 255) / 256, 256, 0, stream>>>(sup_src, sup_dst, pidx);
  k_qnode<<<(NN + 255) / 256, 256, 0, stream>>>(pidx, sup_src, sup_dst, qnode);
  k_qedge<<<(EMn + 255) / 256, 256, 0, stream>>>(msg_dst, qnode, qedge);
  k_big<<<MLPB, 768, 0, stream>>>(qnodes, nscale, qnbrs, nbscale, qunit, qedge,
                                  sup_src, sup_dst, msg_src, dencnt, num,
                                  w0q, w1q, cs0, cs1, b0, g0, be0, b1, g1, be1,
                                  Wp, bp, Ww, bw, sscale, sshift, craw, out);
  k_cong<<<(NN + 255) / 256, 256, 0, stream>>>(dencnt, num, cong);
  k_finish<<<(ESn + 255) / 256, 256, 0, stream>>>(sup_src, sup_dst, cong,
                                                  sscale, sshift, craw, out);
}

// Round 13
// 245.334 us; speedup vs baseline: 2.6143x; 2.6143x over previous
//
#include <hip/hip_runtime.h>
#include <math.h>

namespace {

constexpr int NN  = 50000;
constexpr int CC  = 128;
constexpr int EMn = 1000000;
constexpr int ESn = 200000;
constexpr int MLPB = 256;            // persistent blocks (1 per CU)
constexpr int WPB  = 12;             // waves per block
constexpr int NTILES = ESn / 16;     // 12500 tiles of 16 edges
constexpr int NWAVES = MLPB * WPB;   // 3072

using i32x4 = __attribute__((ext_vector_type(4))) int;

__device__ __forceinline__ float softplusf(float x) {
  return (x > 20.f) ? x : log1pf(expf(x));
}
__device__ __forceinline__ int sdot4i(unsigned a, unsigned b, int c) {
#if __has_builtin(__builtin_amdgcn_sdot4)
  return __builtin_amdgcn_sdot4((int)a, (int)b, c, false);
#else
  int r = c;
#pragma unroll
  for (int k = 0; k < 4; k++) {
    int xa = ((int)(a << (24 - 8 * k))) >> 24;
    int xb = ((int)(b << (24 - 8 * k))) >> 24;
    r += xa * xb;
  }
  return r;
#endif
}
__device__ __forceinline__ unsigned pack4(float a, float b, float c, float d) {
  int ia = __float2int_rn(a), ib = __float2int_rn(b);
  int ic = __float2int_rn(c), id = __float2int_rn(d);
  return (unsigned)(ia & 255) | ((unsigned)(ib & 255) << 8) |
         ((unsigned)(ic & 255) << 16) | ((unsigned)(id & 255) << 24);
}

// ---- K0: init scratch ----
__global__ void k_init(int* __restrict__ pidx, double* __restrict__ dencnt,
                       float* __restrict__ num) {
  int i = blockIdx.x * blockDim.x + threadIdx.x;
  if (i < NN) { pidx[i] = -1; dencnt[i] = 0.0; num[i] = 0.f; }
}

// ---- K_cvtq: per-row int8 quantization of nodes/nbrs ----
__global__ void k_cvtq(const float* __restrict__ nodes, const float* __restrict__ nbrs,
                       char* __restrict__ qnodes, char* __restrict__ qunit,
                       char* __restrict__ qnbrs, float* __restrict__ nscale,
                       float* __restrict__ nbscale) {
  int row = blockIdx.x * 16 + (threadIdx.x >> 4);
  int li = threadIdx.x & 15;
  if (row >= 2 * NN) return;
  bool isn = row < NN;
  int r = isn ? row : row - NN;
  const float* src = (isn ? nodes : nbrs) + (size_t)r * CC;
  float4 x0 = *(const float4*)(src + li * 8);
  float4 x1 = *(const float4*)(src + li * 8 + 4);
  float v[8] = {x0.x, x0.y, x0.z, x0.w, x1.x, x1.y, x1.z, x1.w};
  float amax = 0.f, sq = 0.f;
#pragma unroll
  for (int j = 0; j < 8; j++) { amax = fmaxf(amax, fabsf(v[j])); sq += v[j] * v[j]; }
#pragma unroll
  for (int off = 1; off < 16; off <<= 1) {
    amax = fmaxf(amax, __shfl_xor(amax, off, 64));
    sq += __shfl_xor(sq, off, 64);
  }
  amax = fmaxf(amax, 1e-8f);
  float rs = 127.f / amax;
  uint2 p;
  p.x = pack4(v[0] * rs, v[1] * rs, v[2] * rs, v[3] * rs);
  p.y = pack4(v[4] * rs, v[5] * rs, v[6] * rs, v[7] * rs);
  if (isn) {
    *(uint2*)(qnodes + (size_t)r * CC + li * 8) = p;
    float ru = 127.f / fmaxf(sqrtf(sq), 1e-8f);
    uint2 pu;
    pu.x = pack4(v[0] * ru, v[1] * ru, v[2] * ru, v[3] * ru);
    pu.y = pack4(v[4] * ru, v[5] * ru, v[6] * ru, v[7] * ru);
    *(uint2*)(qunit + (size_t)r * CC + li * 8) = pu;
    if (li == 0) nscale[r] = amax / 127.f;
  } else {
    *(uint2*)(qnbrs + (size_t)r * CC + li * 8) = p;
    if (li == 0) nbscale[r] = amax / 127.f;
  }
}

// ---- K2: partner_index scatter-max ----
__global__ void k_partner(const int* __restrict__ ss, const int* __restrict__ sd,
                          int* __restrict__ pidx) {
  int i = blockIdx.x * blockDim.x + threadIdx.x;
  if (i >= 2 * ESn) return;
  int partner = (i < ESn) ? sd[i] : ss[i - ESn];
  atomicMax(&pidx[partner], i);
}

// ---- K_qnode ----
__global__ void k_qnode(const int* __restrict__ pidx, const int* __restrict__ ss,
                        const int* __restrict__ sd, int* __restrict__ qnode) {
  int n = blockIdx.x * blockDim.x + threadIdx.x;
  if (n >= NN) return;
  int pi = pidx[n];
  qnode[n] = (pi < 0) ? -1 : ((pi < ESn) ? ss[pi] : sd[pi - ESn]);
}

// ---- K_prep2: int8 per-col quant of W0/W1 into swizzled [col][k] layout ----
__global__ __launch_bounds__(256) void k_prep2(const float* __restrict__ W0,
                                               const float* __restrict__ W1,
                                               char* __restrict__ w0q, char* __restrict__ w1q,
                                               float* __restrict__ cs0, float* __restrict__ cs1) {
  __shared__ float wmax[4];
  int c = blockIdx.x;
  int k = threadIdx.x;
  bool is0 = c < 256;
  int col = is0 ? c : c - 256;
  float v = is0 ? W0[(size_t)k * 256 + col] : W1[(size_t)k * 128 + col];
  float am = fabsf(v);
#pragma unroll
  for (int off = 1; off < 64; off <<= 1) am = fmaxf(am, __shfl_xor(am, off, 64));
  if ((k & 63) == 0) wmax[k >> 6] = am;
  __syncthreads();
  float amax = fmaxf(fmaxf(wmax[0], wmax[1]), fmaxf(wmax[2], wmax[3]));
  amax = fmaxf(amax, 1e-12f);
  int q = __float2int_rn(v * (127.f / amax));
  char* dst = is0 ? w0q : w1q;
  dst[(size_t)col * 256 + ((((k >> 4) ^ (col & 15))) << 4) + (k & 15)] = (char)q;
  if (k == 0) (is0 ? cs0 : cs1)[col] = amax / 127.f;
}

// ---- K5: cong_node (decode packed den+cnt) ----
__global__ void k_cong(const double* __restrict__ dencnt, const float* __restrict__ num,
                       float* __restrict__ cong) {
  int n = blockIdx.x * blockDim.x + threadIdx.x;
  if (n >= NN) return;
  double dc = dencnt[n];
  double cnt = floor(dc * (1.0 / 4294967296.0) + 0.5);
  double den = dc - cnt * 4294967296.0;
  cong[n] = (cnt > 0.0) ? (float)(((double)num[n] / fmax(den, 1e-30)) / cnt) : 0.f;
}

// ---- K_finish: P_cong column + coeff ----
__global__ void k_finish(const int* __restrict__ ssrc, const int* __restrict__ sdst,
                         const float* __restrict__ cong, const float* __restrict__ sscale,
                         const float* __restrict__ sshift, const float* __restrict__ craw,
                         float* __restrict__ out) {
  int i = blockIdx.x * blockDim.x + threadIdx.x;
  float u0 = softplusf(craw[0]), u1 = softplusf(craw[1]), u2 = softplusf(craw[2]);
  float usum = u0 + u1 + u2;
  float c2 = u2 / usum;
  if (i < ESn)
    out[3 * i + 2] = c2 * (sscale[0] * (cong[ssrc[i]] + cong[sdst[i]] + sshift[0]));
  if (i == 0) {
    out[4 * ESn + 0] = u0 / usum;
    out[4 * ESn + 1] = u1 / usum;
    out[4 * ESn + 2] = c2;
  }
}

// ---- K_big: zero-barrier wave-autonomous MLP (i8 MFMA, LDS weights) + cos phase ----
__global__ __launch_bounds__(768, 3) void k_big(
    const char* __restrict__ qnodes, const float* __restrict__ nscale,
    const char* __restrict__ qnbrs, const float* __restrict__ nbscale,
    const char* __restrict__ qunit, const int* __restrict__ qnode,
    const int* __restrict__ ssrc, const int* __restrict__ sdst,
    const int* __restrict__ ms, const int* __restrict__ md,
    double* __restrict__ dencnt, float* __restrict__ num,
    const char* __restrict__ w0q, const char* __restrict__ w1q,
    const float* __restrict__ cs0g, const float* __restrict__ cs1g,
    const float* __restrict__ b0, const float* __restrict__ g0, const float* __restrict__ be0,
    const float* __restrict__ b1, const float* __restrict__ g1, const float* __restrict__ be1,
    const float* __restrict__ Wp, const float* __restrict__ bp,
    const float* __restrict__ Ww, const float* __restrict__ bw,
    const float* __restrict__ sscale, const float* __restrict__ sshift,
    const float* __restrict__ craw, float* __restrict__ out) {
  __shared__ char  w0s[65536];       // W0 int8 [256 col][256 k], granule-XOR swizzled
  __shared__ char  w1s[32768];       // W1 int8 [128 col][256 k]
  __shared__ float prm[1792];        // cs0,b0,g0,be0 (256ea) | cs1,b1,g1,be1,Wp,Ww (128ea)
  __shared__ char  hln[WPB][4096];   // per-wave h_ln int8 [16 r][256 c] swizzled

  const int t = threadIdx.x;
  for (int i = t; i < 4096; i += 768) ((uint4*)w0s)[i] = ((const uint4*)w0q)[i];
  for (int i = t; i < 2048; i += 768) ((uint4*)w1s)[i] = ((const uint4*)w1q)[i];
  if (t < 256) { prm[t] = cs0g[t]; prm[256 + t] = b0[t]; prm[512 + t] = g0[t]; prm[768 + t] = be0[t]; }
  if (t < 128) { prm[1024 + t] = cs1g[t]; prm[1152 + t] = b1[t]; prm[1280 + t] = g1[t];
                 prm[1408 + t] = be1[t];  prm[1536 + t] = Wp[t]; prm[1664 + t] = Ww[t]; }
  __syncthreads();                   // the ONLY block barrier

  const int wv = t >> 6, l = t & 63;
  const int e16 = l & 15, ch = l >> 4;
  const int gw = blockIdx.x * WPB + wv;
  char* hw = hln[wv];

  float u0 = softplusf(craw[0]), u1 = softplusf(craw[1]), u2 = softplusf(craw[2]);
  float us = u0 + u1 + u2, c0 = u0 / us, c1 = u1 / us;
  float sc = sscale[0], sh = sshift[0], bp0 = bp[0], bw0 = bw[0], ww128 = Ww[128];

  for (int tile = gw; tile < NTILES; tile += NWAVES) {
    const int s0 = tile * 16;
    // ---- gathers: lane handles edge e16, chunks ch of nodes(2x16B) + nbrs(2x16B) each side ----
    int eg = s0 + e16;
    int es = ssrc[eg], ed = sdst[eg];
    float sxs = nscale[es], sxd = nscale[ed];
    const uint4* xp = (const uint4*)(qnodes + (size_t)es * CC);
    const uint4* yp = (const uint4*)(qnodes + (size_t)ed * CC);
    uint4 X0 = xp[ch], X1 = xp[4 + ch], Y0 = yp[ch], Y1 = yp[4 + ch];
    const uint4* nxp = (const uint4*)(qnbrs + (size_t)es * CC);
    const uint4* nyp = (const uint4*)(qnbrs + (size_t)ed * CC);
    uint4 NX0 = nxp[2 * ch], NX1 = nxp[2 * ch + 1];
    uint4 NY0 = nyp[2 * ch], NY1 = nyp[2 * ch + 1];
    float nbs = nbscale[es] * nbscale[ed];

    // ---- nbrs similarity ----
    int sa = 0;
    sa = sdot4i(NX0.x, NY0.x, sa); sa = sdot4i(NX0.y, NY0.y, sa);
    sa = sdot4i(NX0.z, NY0.z, sa); sa = sdot4i(NX0.w, NY0.w, sa);
    sa = sdot4i(NX1.x, NY1.x, sa); sa = sdot4i(NX1.y, NY1.y, sa);
    sa = sdot4i(NX1.z, NY1.z, sa); sa = sdot4i(NX1.w, NY1.w, sa);
    sa += __shfl_xor(sa, 16, 64); sa += __shfl_xor(sa, 32, 64);
    float nsim = (float)sa * nbs;

    unsigned xw[8] = {X0.x, X0.y, X0.z, X0.w, X1.x, X1.y, X1.z, X1.w};
    unsigned yw[8] = {Y0.x, Y0.y, Y0.z, Y0.w, Y1.x, Y1.y, Y1.z, Y1.w};

    // ---- pass 1: row amax of combined (a|m) over this edge ----
    float amax = 1e-8f;
#pragma unroll
    for (int d = 0; d < 8; d++)
#pragma unroll
      for (int b = 0; b < 4; b++) {
        float fx = (float)((int)(xw[d] << (24 - 8 * b)) >> 24) * sxs;
        float fy = (float)((int)(yw[d] << (24 - 8 * b)) >> 24) * sxd;
        amax = fmaxf(amax, fmaxf(fabsf(fx + fy), fabsf(fx * fy)));
      }
    amax = fmaxf(amax, __shfl_xor(amax, 16, 64));
    amax = fmaxf(amax, __shfl_xor(amax, 32, 64));
    float rqz = 127.f / amax, rsc = amax / 127.f;

    // ---- pass 2: build 4 int8 A-frags (ksteps: a0,a1,m0,m1) ----
    i32x4 fr[4];
#pragma unroll
    for (int half = 0; half < 2; half++) {
#pragma unroll
      for (int d = 0; d < 4; d++) {
        unsigned xd = xw[half * 4 + d], yd = yw[half * 4 + d];
        float a_[4], m_[4];
#pragma unroll
        for (int b = 0; b < 4; b++) {
          float fx = (float)((int)(xd << (24 - 8 * b)) >> 24) * sxs;
          float fy = (float)((int)(yd << (24 - 8 * b)) >> 24) * sxd;
          a_[b] = fx + fy; m_[b] = fx * fy;
        }
        fr[half][d]     = (int)pack4(a_[0] * rqz, a_[1] * rqz, a_[2] * rqz, a_[3] * rqz);
        fr[2 + half][d] = (int)pack4(m_[0] * rqz, m_[1] * rqz, m_[2] * rqz, m_[3] * rqz);
      }
    }
    float rsrow[4];
#pragma unroll
    for (int j = 0; j < 4; j++) rsrow[j] = __shfl(rsc, (ch << 2) + j, 64);

    // ---- GEMM1: i8 MFMA, weights from LDS ----
    i32x4 acc[16];
#pragma unroll
    for (int nf = 0; nf < 16; nf++) acc[nf] = (i32x4){0, 0, 0, 0};
#pragma unroll
    for (int s = 0; s < 4; s++) {
      int gofs = (((s * 4 + ch) ^ e16) << 4);
#pragma unroll
      for (int nf = 0; nf < 16; nf++) {
        i32x4 bfr = *(const i32x4*)&w0s[(nf * 16 + e16) * 256 + gofs];
        acc[nf] = __builtin_amdgcn_mfma_i32_16x16x64_i8(fr[s], bfr, acc[nf], 0, 0, 0);
      }
    }

    // ---- LN1 stats (in-register + 16-lane shuffles) ----
    float sj[4] = {0, 0, 0, 0}, qj[4] = {0, 0, 0, 0};
#pragma unroll
    for (int nf = 0; nf < 16; nf++) {
      float cs = prm[nf * 16 + e16], bb = prm[256 + nf * 16 + e16];
#pragma unroll
      for (int j = 0; j < 4; j++) {
        float h = (float)acc[nf][j] * rsrow[j] * cs + bb;
        sj[j] += h; qj[j] += h * h;
      }
    }
    float mu[4], rstd[4];
#pragma unroll
    for (int j = 0; j < 4; j++) {
      float s = sj[j], q = qj[j];
#pragma unroll
      for (int off = 1; off < 16; off <<= 1) { s += __shfl_xor(s, off, 64); q += __shfl_xor(q, off, 64); }
      mu[j] = s * (1.f / 256.f);
      rstd[j] = rsqrtf(q * (1.f / 256.f) - mu[j] * mu[j] + 1e-5f);
    }
    // ---- normalize + relu (store v into acc bits), track row max ----
    float hmax[4] = {1e-8f, 1e-8f, 1e-8f, 1e-8f};
#pragma unroll
    for (int nf = 0; nf < 16; nf++) {
      float cs = prm[nf * 16 + e16], bb = prm[256 + nf * 16 + e16];
      float gg = prm[512 + nf * 16 + e16], be = prm[768 + nf * 16 + e16];
#pragma unroll
      for (int j = 0; j < 4; j++) {
        float h = (float)acc[nf][j] * rsrow[j] * cs + bb;
        float v = fmaxf((h - mu[j]) * rstd[j] * gg + be, 0.f);
        hmax[j] = fmaxf(hmax[j], v);
        acc[nf][j] = __float_as_int(v);
      }
    }
    float rq2[4], rs2[4];
#pragma unroll
    for (int j = 0; j < 4; j++) {
      float m = hmax[j];
#pragma unroll
      for (int off = 1; off < 16; off <<= 1) m = fmaxf(m, __shfl_xor(m, off, 64));
      rq2[j] = 127.f / m; rs2[j] = m / 127.f;
    }
    // ---- write h_ln int8 to private LDS tile (swizzled) ----
#pragma unroll
    for (int nf = 0; nf < 16; nf++) {
#pragma unroll
      for (int j = 0; j < 4; j++) {
        int r = (ch << 2) + j;
        int qv = __float2int_rn(__int_as_float(acc[nf][j]) * rq2[j]);
        hw[r * 256 + ((nf ^ r) << 4) + e16] = (char)qv;
      }
    }

    // ---- GEMM2: i8 MFMA, A from private LDS, B from w1s ----
    i32x4 acc2[8];
#pragma unroll
    for (int nf = 0; nf < 8; nf++) acc2[nf] = (i32x4){0, 0, 0, 0};
#pragma unroll
    for (int s = 0; s < 4; s++) {
      int gofs = (((s * 4 + ch) ^ e16) << 4);
      i32x4 af = *(const i32x4*)&hw[e16 * 256 + gofs];
#pragma unroll
      for (int nf = 0; nf < 8; nf++) {
        i32x4 bfr = *(const i32x4*)&w1s[(nf * 16 + e16) * 256 + gofs];
        acc2[nf] = __builtin_amdgcn_mfma_i32_16x16x64_i8(af, bfr, acc2[nf], 0, 0, 0);
      }
    }

    // ---- LN2 + heads ----
    float s2[4] = {0, 0, 0, 0}, q2[4] = {0, 0, 0, 0};
#pragma unroll
    for (int nf = 0; nf < 8; nf++) {
      float cs = prm[1024 + nf * 16 + e16], bb = prm[1152 + nf * 16 + e16];
#pragma unroll
      for (int j = 0; j < 4; j++) {
        float ef = (float)acc2[nf][j] * rs2[j] * cs + bb;
        s2[j] += ef; q2[j] += ef * ef;
      }
    }
    float mu2[4], rstd2[4];
#pragma unroll
    for (int j = 0; j < 4; j++) {
      float s = s2[j], q = q2[j];
#pragma unroll
      for (int off = 1; off < 16; off <<= 1) { s += __shfl_xor(s, off, 64); q += __shfl_xor(q, off, 64); }
      mu2[j] = s * (1.f / 128.f);
      rstd2[j] = rsqrtf(q * (1.f / 128.f) - mu2[j] * mu2[j] + 1e-5f);
    }
    float pd[4] = {0, 0, 0, 0}, ws_[4] = {0, 0, 0, 0};
#pragma unroll
    for (int nf = 0; nf < 8; nf++) {
      float cs = prm[1024 + nf * 16 + e16], bb = prm[1152 + nf * 16 + e16];
      float gg = prm[1280 + nf * 16 + e16], be = prm[1408 + nf * 16 + e16];
      float wp_ = prm[1536 + nf * 16 + e16], ww_ = prm[1664 + nf * 16 + e16];
#pragma unroll
      for (int j = 0; j < 4; j++) {
        float ef = (float)acc2[nf][j] * rs2[j] * cs + bb;
        float v = fmaxf((ef - mu2[j]) * rstd2[j] * gg + be, 0.f);
        pd[j] += v * wp_; ws_[j] += v * ww_;
      }
    }
#pragma unroll
    for (int j = 0; j < 4; j++)
#pragma unroll
      for (int off = 1; off < 16; off <<= 1) {
        pd[j] += __shfl_xor(pd[j], off, 64);
        ws_[j] += __shfl_xor(ws_[j], off, 64);
      }
    float nsr[4];
#pragma unroll
    for (int j = 0; j < 4; j++) nsr[j] = __shfl(nsim, (ch << 2) + j, 64);
    if (e16 == 0) {
#pragma unroll
      for (int j = 0; j < 4; j++) {
        int sidx = s0 + (ch << 2) + j;
        out[3 * sidx + 0] = c0 * (pd[j] + bp0);
        out[3 * sidx + 1] = c1 * (sc * (nsr[j] + sh));
        out[3 * ESn + sidx] = fmaxf(ws_[j] + nsr[j] * ww128 + bw0, 0.f);
      }
    }
  }

  // ---- cos phase (all waves, after their MLP tiles) ----
  const int li8 = l & 7, grp = l >> 3;
  for (int i = gw; i < EMn / 8; i += NWAVES) {
    int e = i * 8 + grp;
    int q = qnode[md[e]];
    if (q < 0) continue;
    int s = ms[e];
    uint4 a = ((const uint4*)(qunit + (size_t)q * CC))[li8];
    uint4 b = ((const uint4*)(qunit + (size_t)s * CC))[li8];
    int acc = 0;
    acc = sdot4i(a.x, b.x, acc); acc = sdot4i(a.y, b.y, acc);
    acc = sdot4i(a.z, b.z, acc); acc = sdot4i(a.w, b.w, acc);
    acc += __shfl_xor(acc, 1, 64);
    acc += __shfl_xor(acc, 2, 64);
    acc += __shfl_xor(acc, 4, 64);
    if (li8 == 0) {
      float cv = (float)acc * (1.0f / (127.f * 127.f));
      float wvv = expf(10.0f * cv);
      atomicAdd(&dencnt[q], (double)wvv + 4294967296.0);   // den + cnt*2^32 packed
      atomicAdd(&num[q], wvv * cv);
    }
  }
}

} // namespace

extern "C" void kernel_launch(void* const* d_in, const int* in_sizes, int n_in,
                              void* d_out, int out_size, void* d_ws, size_t ws_size,
                              hipStream_t stream) {
  (void)in_sizes; (void)n_in; (void)out_size; (void)ws_size;
  const float* nodes  = (const float*)d_in[0];
  const float* nbrs   = (const float*)d_in[1];
  const int* sup_src  = (const int*)d_in[2];
  const int* sup_dst  = (const int*)d_in[3];
  const int* msg_src  = (const int*)d_in[4];
  const int* msg_dst  = (const int*)d_in[5];
  // d_in[6] message_edgestr: dead
  const float* W0  = (const float*)d_in[7];
  const float* b0  = (const float*)d_in[8];
  const float* g0  = (const float*)d_in[9];
  const float* be0 = (const float*)d_in[10];
  const float* W1  = (const float*)d_in[11];
  const float* b1  = (const float*)d_in[12];
  const float* g1  = (const float*)d_in[13];
  const float* be1 = (const float*)d_in[14];
  const float* Wp  = (const float*)d_in[15];
  const float* bp  = (const float*)d_in[16];
  const float* Ww  = (const float*)d_in[17];
  const float* bw  = (const float*)d_in[18];
  const float* sscale = (const float*)d_in[19];
  const float* sshift = (const float*)d_in[20];
  const float* craw   = (const float*)d_in[21];
  // d_in[22..27] mm_*: dead
  float* out = (float*)d_out;

  char* p = (char*)d_ws;
  auto take = [&](size_t bytes) -> char* {
    char* r = p; p += (bytes + 255) & ~(size_t)255; return r;
  };
  char*   w0q     = take((size_t)256 * 256);
  char*   w1q     = take((size_t)128 * 256);
  float*  cs0     = (float*)take((size_t)256 * 4);
  float*  cs1     = (float*)take((size_t)128 * 4);
  char*   qnodes  = take((size_t)NN * CC);
  char*   qunit   = take((size_t)NN * CC);
  char*   qnbrs   = take((size_t)NN * CC);
  float*  nscale  = (float*)take((size_t)NN * 4);
  float*  nbscale = (float*)take((size_t)NN * 4);
  int*    pidx    = (int*)take((size_t)NN * 4);
  int*    qnode   = (int*)take((size_t)NN * 4);
  double* dencnt  = (double*)take((size_t)NN * 8);
  float*  num     = (float*)take((size_t)NN * 4);
  float*  cong    = (float*)take((size_t)NN * 4);

  k_init<<<(NN + 255) / 256, 256, 0, stream>>>(pidx, dencnt, num);
  k_cvtq<<<(2 * NN + 15) / 16, 256, 0, stream>>>(nodes, nbrs, qnodes, qunit, qnbrs,
                                                 nscale, nbscale);
  k_prep2<<<384, 256, 0, stream>>>(W0, W1, w0q, w1q, cs0, cs1);
  k_partner<<<(2 * ESn + 255) / 256, 256, 0, stream>>>(sup_src, sup_dst, pidx);
  k_qnode<<<(NN + 255) / 256, 256, 0, stream>>>(pidx, sup_src, sup_dst, qnode);
  k_big<<<MLPB, 768, 0, stream>>>(qnodes, nscale, qnbrs, nbscale, qunit, qnode,
                                  sup_src, sup_dst, msg_src, msg_dst, dencnt, num,
                                  w0q, w1q, cs0, cs1, b0, g0, be0, b1, g1, be1,
                                  Wp, bp, Ww, bw, sscale, sshift, craw, out);
  k_cong<<<(NN + 255) / 256, 256, 0, stream>>>(dencnt, num, cong);
  k_finish<<<(ESn + 255) / 256, 256, 0, stream>>>(sup_src, sup_dst, cong,
                                                  sscale, sshift, craw, out);
}